// Round 1
// baseline (1187.110 us; speedup 1.0000x reference)
//
#include <hip/hip_runtime.h>
#include <math.h>

typedef __attribute__((ext_vector_type(8))) short short8;   // 8 bf16 = 4 VGPR (MFMA A/B frag)
typedef __attribute__((ext_vector_type(4))) float f32x4;    // MFMA acc frag
typedef __attribute__((ext_vector_type(2))) float f32x2;

#define PI_OVER_CUTOFF 0.31415926535897932f
#define SLOPE 0.015f

__device__ __forceinline__ unsigned short f2bf(float x) {
    unsigned u = __float_as_uint(x);
    return (unsigned short)((u + 0x7FFFu + ((u >> 16) & 1u)) >> 16);   // RNE
}
__device__ __forceinline__ float bf2f(unsigned short s) {
    return __uint_as_float(((unsigned)s) << 16);
}

// ---------------- kernel 0: weights -> bf16, B^T layout, pad, fold identity ---
__global__ void prep_weights(const float* __restrict__ w1, const float* __restrict__ w2,
                             const float* __restrict__ w3, const float* __restrict__ wo,
                             unsigned short* __restrict__ w1p, unsigned short* __restrict__ w2b,
                             unsigned short* __restrict__ w3b, unsigned short* __restrict__ wob) {
    int i = blockIdx.x * 256 + threadIdx.x;
    if (i < 128 * 64) {                       // w1: [128][50] -> [128][64] zero-padded
        int c = i >> 6, k = i & 63;
        w1p[i] = (k < 50) ? f2bf(w1[c * 50 + k]) : (unsigned short)0;
    }
    if (i < 128 * 128) {
        int c = i >> 7, k = i & 127;
        w2b[i] = f2bf(w2[i]);
        w3b[i] = f2bf(w3[i]);
        wob[i] = f2bf(wo[i] + ((c == k) ? 1.0f : 0.0f));  // fold "+e" residual into weight
    }
}

// ---------------- kernel 1: vp = v @ lin_w.T  -> bf16 [N][128] -----------------
__global__ __launch_bounds__(256) void vp_gemm(const float* __restrict__ v,
                                               const float* __restrict__ lin_w,
                                               unsigned short* __restrict__ vp, int nnodes) {
    const int tid = threadIdx.x;
    const int lane = tid & 63;
    const int wv = tid >> 6;          // wave 0..3 -> col strip of 32
    const int l15 = lane & 15;
    const int l4 = lane >> 4;
    const int r0 = blockIdx.x * 64;
    const int c0 = wv * 32;

    f32x4 acc[4][2] = {};
#pragma unroll
    for (int kf = 0; kf < 4; ++kf) {
        short8 a[4];
#pragma unroll
        for (int mf = 0; mf < 4; ++mf) {
            int row = r0 + mf * 16 + l15;
            f32x4 x0 = {}, x1 = {};
            if (row < nnodes) {
                const float* p = v + (size_t)row * 128 + kf * 32 + l4 * 8;
                x0 = *reinterpret_cast<const f32x4*>(p);
                x1 = *reinterpret_cast<const f32x4*>(p + 4);
            }
            short8 t;
#pragma unroll
            for (int j = 0; j < 4; ++j) { t[j] = (short)f2bf(x0[j]); t[4 + j] = (short)f2bf(x1[j]); }
            a[mf] = t;
        }
        short8 b[2];
#pragma unroll
        for (int nf = 0; nf < 2; ++nf) {
            const float* p = lin_w + (size_t)(c0 + nf * 16 + l15) * 128 + kf * 32 + l4 * 8;
            f32x4 x0 = *reinterpret_cast<const f32x4*>(p);
            f32x4 x1 = *reinterpret_cast<const f32x4*>(p + 4);
            short8 t;
#pragma unroll
            for (int j = 0; j < 4; ++j) { t[j] = (short)f2bf(x0[j]); t[4 + j] = (short)f2bf(x1[j]); }
            b[nf] = t;
        }
#pragma unroll
        for (int mf = 0; mf < 4; ++mf)
#pragma unroll
            for (int nf = 0; nf < 2; ++nf)
                acc[mf][nf] = __builtin_amdgcn_mfma_f32_16x16x32_bf16(a[mf], b[nf], acc[mf][nf], 0, 0, 0);
    }
#pragma unroll
    for (int mf = 0; mf < 4; ++mf)
#pragma unroll
        for (int nf = 0; nf < 2; ++nf)
#pragma unroll
            for (int q = 0; q < 4; ++q) {
                int row = r0 + mf * 16 + l4 * 4 + q;
                if (row < nnodes)
                    vp[(size_t)row * 128 + c0 + nf * 16 + l15] = f2bf(acc[mf][nf][q]);
            }
}

// ---------------- kernel 2: fused edge chain ----------------------------------
// tile = 128 edges x 128 filters, 4 waves, each wave a 64x64 sub-tile.
// LDS: one in-place h buffer (XOR-swizzled), emb staging, C/j arrays. 49KB -> 3 blk/CU.
__global__ __launch_bounds__(256) void fused_edge(
    const float* __restrict__ dist, const float* __restrict__ dist_emb,
    const int* __restrict__ edge_index,
    const float* __restrict__ b1, const float* __restrict__ b2,
    const float* __restrict__ b3, const float* __restrict__ bo,
    const unsigned short* __restrict__ vp,
    const unsigned short* __restrict__ w1p, const unsigned short* __restrict__ w2b,
    const unsigned short* __restrict__ w3b, const unsigned short* __restrict__ wob,
    float* __restrict__ out) {
    __shared__ __align__(16) unsigned char lds_h[128 * 256];  // [128][128] bf16, swizzled
    __shared__ __align__(16) unsigned char lds_e[128 * 128];  // [128][64]  bf16, swizzled
    __shared__ float ldsC[128];
    __shared__ int ldsJ[128];

    const int tid = threadIdx.x;
    const int lane = tid & 63;
    const int wv = tid >> 6;
    const int wr = (wv >> 1) * 64;    // wave row base in tile
    const int wc = (wv & 1) * 64;     // wave col base in tile
    const int l15 = lane & 15;
    const int l4 = lane >> 4;
    const long eBase = (long)blockIdx.x * 128;

    // ---- preamble: cutoff C, source index j, gaussian emb tile (pad K 50->64) ----
    if (tid < 128) {
        float d = dist[eBase + tid];
        ldsC[tid] = 0.5f * (cosf(d * PI_OVER_CUTOFF) + 1.0f);
        ldsJ[tid] = edge_index[eBase + tid];   // row 0 of [2][E]
    }
#pragma unroll
    for (int it = 0; it < 16; ++it) {
        int idx = tid + it * 256;        // 128 rows x 32 bf16-pairs
        int r = idx >> 5;
        int k2 = (idx & 31) * 2;
        unsigned pk = 0;
        if (k2 < 50) {
            f32x2 x = *reinterpret_cast<const f32x2*>(dist_emb + (size_t)(eBase + r) * 50 + k2);
            pk = (unsigned)f2bf(x[0]) | ((unsigned)f2bf(x[1]) << 16);
        }
        *reinterpret_cast<unsigned*>(lds_e + r * 128 + ((k2 * 2) ^ ((r & 7) << 4))) = pk;
    }
    __syncthreads();

    short8 af[4][4];

    // ================= stage 1: h1 = leaky(emb @ w1p.T + b1) =================
    {
        f32x4 acc[4][4] = {};
#pragma unroll
        for (int mf = 0; mf < 4; ++mf)
#pragma unroll
            for (int kf = 0; kf < 2; ++kf) {
                int row = wr + mf * 16 + l15;
                int cb = (kf * 32 + l4 * 8) * 2;
                af[mf][kf] = *reinterpret_cast<const short8*>(lds_e + row * 128 + (cb ^ ((row & 7) << 4)));
            }
#pragma unroll
        for (int kf = 0; kf < 2; ++kf) {
            short8 bf[4];
#pragma unroll
            for (int nf = 0; nf < 4; ++nf)
                bf[nf] = *reinterpret_cast<const short8*>(w1p + (size_t)(wc + nf * 16 + l15) * 64 + kf * 32 + l4 * 8);
#pragma unroll
            for (int mf = 0; mf < 4; ++mf)
#pragma unroll
                for (int nf = 0; nf < 4; ++nf)
                    acc[mf][nf] = __builtin_amdgcn_mfma_f32_16x16x32_bf16(af[mf][kf], bf[nf], acc[mf][nf], 0, 0, 0);
        }
        float bv[4];
#pragma unroll
        for (int nf = 0; nf < 4; ++nf) bv[nf] = b1[wc + nf * 16 + l15];
#pragma unroll
        for (int mf = 0; mf < 4; ++mf)
#pragma unroll
            for (int nf = 0; nf < 4; ++nf)
#pragma unroll
                for (int q = 0; q < 4; ++q) {
                    int row = wr + mf * 16 + l4 * 4 + q;
                    int col = wc + nf * 16 + l15;
                    float x = acc[mf][nf][q] + bv[nf];
                    x = fmaxf(x, SLOPE * x);
                    *reinterpret_cast<unsigned short*>(lds_h + row * 256 + ((col * 2) ^ ((row & 7) << 4))) = f2bf(x);
                }
    }
    __syncthreads();

    // ================= stage 2: h2 = leaky(h1 @ w2.T + b2) (in-place) =========
    {
#pragma unroll
        for (int mf = 0; mf < 4; ++mf)
#pragma unroll
            for (int kf = 0; kf < 4; ++kf) {
                int row = wr + mf * 16 + l15;
                int cb = (kf * 32 + l4 * 8) * 2;
                af[mf][kf] = *reinterpret_cast<const short8*>(lds_h + row * 256 + (cb ^ ((row & 7) << 4)));
            }
        __syncthreads();   // all reads done before overwrite
        f32x4 acc[4][4] = {};
#pragma unroll
        for (int kf = 0; kf < 4; ++kf) {
            short8 bf[4];
#pragma unroll
            for (int nf = 0; nf < 4; ++nf)
                bf[nf] = *reinterpret_cast<const short8*>(w2b + (size_t)(wc + nf * 16 + l15) * 128 + kf * 32 + l4 * 8);
#pragma unroll
            for (int mf = 0; mf < 4; ++mf)
#pragma unroll
                for (int nf = 0; nf < 4; ++nf)
                    acc[mf][nf] = __builtin_amdgcn_mfma_f32_16x16x32_bf16(af[mf][kf], bf[nf], acc[mf][nf], 0, 0, 0);
        }
        float bv[4];
#pragma unroll
        for (int nf = 0; nf < 4; ++nf) bv[nf] = b2[wc + nf * 16 + l15];
#pragma unroll
        for (int mf = 0; mf < 4; ++mf)
#pragma unroll
            for (int nf = 0; nf < 4; ++nf)
#pragma unroll
                for (int q = 0; q < 4; ++q) {
                    int row = wr + mf * 16 + l4 * 4 + q;
                    int col = wc + nf * 16 + l15;
                    float x = acc[mf][nf][q] + bv[nf];
                    x = fmaxf(x, SLOPE * x);
                    *reinterpret_cast<unsigned short*>(lds_h + row * 256 + ((col * 2) ^ ((row & 7) << 4))) = f2bf(x);
                }
    }
    __syncthreads();

    // ====== stage 3: W = (h2 @ w3.T + b3) * C ; e = vp[j] * W (in-place) ======
    {
#pragma unroll
        for (int mf = 0; mf < 4; ++mf)
#pragma unroll
            for (int kf = 0; kf < 4; ++kf) {
                int row = wr + mf * 16 + l15;
                int cb = (kf * 32 + l4 * 8) * 2;
                af[mf][kf] = *reinterpret_cast<const short8*>(lds_h + row * 256 + (cb ^ ((row & 7) << 4)));
            }
        __syncthreads();
        f32x4 acc[4][4] = {};
#pragma unroll
        for (int kf = 0; kf < 4; ++kf) {
            short8 bf[4];
#pragma unroll
            for (int nf = 0; nf < 4; ++nf)
                bf[nf] = *reinterpret_cast<const short8*>(w3b + (size_t)(wc + nf * 16 + l15) * 128 + kf * 32 + l4 * 8);
#pragma unroll
            for (int mf = 0; mf < 4; ++mf)
#pragma unroll
                for (int nf = 0; nf < 4; ++nf)
                    acc[mf][nf] = __builtin_amdgcn_mfma_f32_16x16x32_bf16(af[mf][kf], bf[nf], acc[mf][nf], 0, 0, 0);
        }
        float bv[4];
#pragma unroll
        for (int nf = 0; nf < 4; ++nf) bv[nf] = b3[wc + nf * 16 + l15];
#pragma unroll
        for (int mf = 0; mf < 4; ++mf)
#pragma unroll
            for (int q = 0; q < 4; ++q) {
                int row = wr + mf * 16 + l4 * 4 + q;
                int jv = ldsJ[row];
                float Cv = ldsC[row];
#pragma unroll
                for (int nf = 0; nf < 4; ++nf) {
                    int col = wc + nf * 16 + l15;
                    float Wv = (acc[mf][nf][q] + bv[nf]) * Cv;
                    float ev = bf2f(vp[(size_t)jv * 128 + col]) * Wv;
                    *reinterpret_cast<unsigned short*>(lds_h + row * 256 + ((col * 2) ^ ((row & 7) << 4))) = f2bf(ev);
                }
            }
    }
    __syncthreads();

    // ====== stage 4: out = e @ (wout + I).T + bo  (residual folded) ===========
    {
#pragma unroll
        for (int mf = 0; mf < 4; ++mf)
#pragma unroll
            for (int kf = 0; kf < 4; ++kf) {
                int row = wr + mf * 16 + l15;
                int cb = (kf * 32 + l4 * 8) * 2;
                af[mf][kf] = *reinterpret_cast<const short8*>(lds_h + row * 256 + (cb ^ ((row & 7) << 4)));
            }
        f32x4 acc[4][4] = {};
#pragma unroll
        for (int kf = 0; kf < 4; ++kf) {
            short8 bf[4];
#pragma unroll
            for (int nf = 0; nf < 4; ++nf)
                bf[nf] = *reinterpret_cast<const short8*>(wob + (size_t)(wc + nf * 16 + l15) * 128 + kf * 32 + l4 * 8);
#pragma unroll
            for (int mf = 0; mf < 4; ++mf)
#pragma unroll
                for (int nf = 0; nf < 4; ++nf)
                    acc[mf][nf] = __builtin_amdgcn_mfma_f32_16x16x32_bf16(af[mf][kf], bf[nf], acc[mf][nf], 0, 0, 0);
        }
        float bv[4];
#pragma unroll
        for (int nf = 0; nf < 4; ++nf) bv[nf] = bo[wc + nf * 16 + l15];
#pragma unroll
        for (int mf = 0; mf < 4; ++mf)
#pragma unroll
            for (int nf = 0; nf < 4; ++nf)
#pragma unroll
                for (int q = 0; q < 4; ++q) {
                    int row = wr + mf * 16 + l4 * 4 + q;
                    int col = wc + nf * 16 + l15;
                    out[(size_t)(eBase + row) * 128 + col] = acc[mf][nf][q] + bv[nf];
                }
    }
}

extern "C" void kernel_launch(void* const* d_in, const int* in_sizes, int n_in,
                              void* d_out, int out_size, void* d_ws, size_t ws_size,
                              hipStream_t stream) {
    const float* v        = (const float*)d_in[0];
    const float* dist     = (const float*)d_in[1];
    const float* dist_emb = (const float*)d_in[2];
    const int*   edge_idx = (const int*)d_in[3];
    const float* lin_w    = (const float*)d_in[4];
    const float* w1 = (const float*)d_in[5];
    const float* b1 = (const float*)d_in[6];
    const float* w2 = (const float*)d_in[7];
    const float* b2 = (const float*)d_in[8];
    const float* w3 = (const float*)d_in[9];
    const float* b3 = (const float*)d_in[10];
    const float* wo = (const float*)d_in[11];
    const float* bo = (const float*)d_in[12];
    float* out = (float*)d_out;

    const int nnodes = in_sizes[0] / 128;   // 50000
    const int E = in_sizes[1];              // 1600000 (multiple of 128)

    unsigned short* vp  = (unsigned short*)d_ws;            // [nnodes][128] bf16
    unsigned short* w1p = vp + (size_t)nnodes * 128;        // [128][64]
    unsigned short* w2b = w1p + 128 * 64;                   // [128][128]
    unsigned short* w3b = w2b + 128 * 128;
    unsigned short* wob = w3b + 128 * 128;

    prep_weights<<<64, 256, 0, stream>>>(w1, w2, w3, wo, w1p, w2b, w3b, wob);
    vp_gemm<<<(nnodes + 63) / 64, 256, 0, stream>>>(v, lin_w, vp, nnodes);
    fused_edge<<<E / 128, 256, 0, stream>>>(dist, dist_emb, edge_idx,
                                            b1, b2, b3, bo, vp,
                                            w1p, w2b, w3b, wob, out);
}

// Round 2
// 945.718 us; speedup vs baseline: 1.2552x; 1.2552x over previous
//
#include <hip/hip_runtime.h>
#include <math.h>

typedef __attribute__((ext_vector_type(8))) short short8;   // 8 bf16 (MFMA A/B frag)
typedef __attribute__((ext_vector_type(4))) float f32x4;    // MFMA acc frag
typedef __attribute__((ext_vector_type(2))) float f32x2;

#define PI_OVER_CUTOFF 0.31415926535897932f
#define SLOPE 0.015f

union S8 { short8 s; unsigned u[4]; };

__device__ __forceinline__ unsigned short f2bf(float x) {
    unsigned u = __float_as_uint(x);
    return (unsigned short)((u + 0x7FFFu + ((u >> 16) & 1u)) >> 16);   // RNE
}
__device__ __forceinline__ float bf2f(unsigned short s) {
    return __uint_as_float(((unsigned)s) << 16);
}
// packed f32x2 -> bf16x2, RNE, one instruction. D.lo = cvt(S0), D.hi = cvt(S1).
__device__ __forceinline__ unsigned cvt_pk_bf16(float lo, float hi) {
    unsigned r;
    asm("v_cvt_pk_bf16_f32 %0, %1, %2" : "=v"(r) : "v"(lo), "v"(hi));
    return r;
}

// ---------------- kernel 0: weights -> bf16, B^T layout, pad, fold identity ---
__global__ void prep_weights(const float* __restrict__ w1, const float* __restrict__ w2,
                             const float* __restrict__ w3, const float* __restrict__ wo,
                             unsigned short* __restrict__ w1p, unsigned short* __restrict__ w2b,
                             unsigned short* __restrict__ w3b, unsigned short* __restrict__ wob) {
    int i = blockIdx.x * 256 + threadIdx.x;
    if (i < 128 * 64) {                       // w1: [128][50] -> [128][64] zero-padded
        int c = i >> 6, k = i & 63;
        w1p[i] = (k < 50) ? f2bf(w1[c * 50 + k]) : (unsigned short)0;
    }
    if (i < 128 * 128) {
        int c = i >> 7, k = i & 127;
        w2b[i] = f2bf(w2[i]);
        w3b[i] = f2bf(w3[i]);
        wob[i] = f2bf(wo[i] + ((c == k) ? 1.0f : 0.0f));  // fold "+e" residual into weight
    }
}

// ---------------- kernel 1: vp = v @ lin_w.T  -> bf16 [N][128] -----------------
__global__ __launch_bounds__(256) void vp_gemm(const float* __restrict__ v,
                                               const float* __restrict__ lin_w,
                                               unsigned short* __restrict__ vp, int nnodes) {
    const int tid = threadIdx.x;
    const int lane = tid & 63;
    const int wv = tid >> 6;          // wave 0..3 -> col strip of 32
    const int l15 = lane & 15;
    const int l4 = lane >> 4;
    const int r0 = blockIdx.x * 64;
    const int c0 = wv * 32;

    f32x4 acc[4][2] = {};
#pragma unroll
    for (int kf = 0; kf < 4; ++kf) {
        short8 a[4];
#pragma unroll
        for (int mf = 0; mf < 4; ++mf) {
            int row = r0 + mf * 16 + l15;
            f32x4 x0 = {}, x1 = {};
            if (row < nnodes) {
                const float* p = v + (size_t)row * 128 + kf * 32 + l4 * 8;
                x0 = *reinterpret_cast<const f32x4*>(p);
                x1 = *reinterpret_cast<const f32x4*>(p + 4);
            }
            short8 t;
#pragma unroll
            for (int j = 0; j < 4; ++j) { t[j] = (short)f2bf(x0[j]); t[4 + j] = (short)f2bf(x1[j]); }
            a[mf] = t;
        }
        short8 b[2];
#pragma unroll
        for (int nf = 0; nf < 2; ++nf) {
            const float* p = lin_w + (size_t)(c0 + nf * 16 + l15) * 128 + kf * 32 + l4 * 8;
            f32x4 x0 = *reinterpret_cast<const f32x4*>(p);
            f32x4 x1 = *reinterpret_cast<const f32x4*>(p + 4);
            short8 t;
#pragma unroll
            for (int j = 0; j < 4; ++j) { t[j] = (short)f2bf(x0[j]); t[4 + j] = (short)f2bf(x1[j]); }
            b[nf] = t;
        }
#pragma unroll
        for (int mf = 0; mf < 4; ++mf)
#pragma unroll
            for (int nf = 0; nf < 2; ++nf)
                acc[mf][nf] = __builtin_amdgcn_mfma_f32_16x16x32_bf16(a[mf], b[nf], acc[mf][nf], 0, 0, 0);
    }
#pragma unroll
    for (int mf = 0; mf < 4; ++mf)
#pragma unroll
        for (int nf = 0; nf < 2; ++nf)
#pragma unroll
            for (int q = 0; q < 4; ++q) {
                int row = r0 + mf * 16 + l4 * 4 + q;
                if (row < nnodes)
                    vp[(size_t)row * 128 + c0 + nf * 16 + l15] = f2bf(acc[mf][nf][q]);
            }
}

// ---------------- kernel 2: fused edge chain, wave-independent ----------------
// Each wave: 32 edges x 128 filters, private 8KB LDS slice, NO __syncthreads.
// Chain: emb(global) -> h1 -> h2 -> W*C -> e=vp[j]*W -> out = e@(wo+I)+bo.
__global__ __launch_bounds__(256, 3) void fused_edge(
    const float* __restrict__ dist, const float* __restrict__ dist_emb,
    const int* __restrict__ edge_index,
    const float* __restrict__ b1, const float* __restrict__ b2,
    const float* __restrict__ b3, const float* __restrict__ bo,
    const unsigned short* __restrict__ vp,
    const unsigned short* __restrict__ w1p, const unsigned short* __restrict__ w2b,
    const unsigned short* __restrict__ w3b, const unsigned short* __restrict__ wob,
    float* __restrict__ out) {
    __shared__ __align__(16) unsigned char lds_h[4][8192];  // per-wave [32 rows][256B], swizzled
    __shared__ float ldsC[4][32];
    __shared__ int   ldsJ[4][32];

    const int tid = threadIdx.x;
    const int lane = tid & 63;
    const int wv = tid >> 6;
    const int l15 = lane & 15;
    const int l4 = lane >> 4;
    const long e0 = (long)blockIdx.x * 128 + wv * 32;
    unsigned char* hb = lds_h[wv];

    // preamble: cutoff C and scaled source index for this wave's 32 edges
    if (lane < 32) {
        float d = dist[e0 + lane];
        ldsC[wv][lane] = 0.5f * (__cosf(d * PI_OVER_CUTOFF) + 1.0f);
        ldsJ[wv][lane] = edge_index[e0 + lane] * 128;
    }

    f32x4 acc[2][8];

    // ================= stage 1: h1 = leaky(emb @ w1p.T + b1) =================
#pragma unroll
    for (int nf = 0; nf < 8; ++nf) {
        float b = b1[nf * 16 + l15];
        acc[0][nf] = (f32x4){b, b, b, b};
        acc[1][nf] = acc[0][nf];
    }
#pragma unroll
    for (int kf = 0; kf < 2; ++kf) {
        S8 a[2];
#pragma unroll
        for (int mf = 0; mf < 2; ++mf) {
            const float* src = dist_emb + (e0 + mf * 16 + l15) * 50 + kf * 32 + l4 * 8;
#pragma unroll
            for (int p = 0; p < 4; ++p) {
                int k2 = kf * 32 + l4 * 8 + 2 * p;
                f32x2 x = (k2 < 50) ? *reinterpret_cast<const f32x2*>(src + 2 * p)
                                    : (f32x2){0.f, 0.f};
                a[mf].u[p] = cvt_pk_bf16(x[0], x[1]);
            }
        }
#pragma unroll
        for (int nf = 0; nf < 8; ++nf) {
            S8 b; b.s = *reinterpret_cast<const short8*>(w1p + (nf * 16 + l15) * 64 + kf * 32 + l4 * 8);
#pragma unroll
            for (int mf = 0; mf < 2; ++mf)
                acc[mf][nf] = __builtin_amdgcn_mfma_f32_16x16x32_bf16(a[mf].s, b.s, acc[mf][nf], 0, 0, 0);
        }
    }
#pragma unroll
    for (int mf = 0; mf < 2; ++mf)
#pragma unroll
        for (int nf = 0; nf < 8; ++nf) {
            f32x4 v = acc[mf][nf];
#pragma unroll
            for (int q = 0; q < 4; ++q) v[q] = fmaxf(v[q], SLOPE * v[q]);
            unsigned p01 = cvt_pk_bf16(v[0], v[1]);
            unsigned p23 = cvt_pk_bf16(v[2], v[3]);
            int col2 = (nf * 16 + l15) * 2;
            int rb = mf * 16 + l4 * 4;
            *(unsigned short*)(hb + (rb + 0) * 256 + (col2 ^ ((l4 * 4 + 0) << 4))) = (unsigned short)p01;
            *(unsigned short*)(hb + (rb + 1) * 256 + (col2 ^ ((l4 * 4 + 1) << 4))) = (unsigned short)(p01 >> 16);
            *(unsigned short*)(hb + (rb + 2) * 256 + (col2 ^ ((l4 * 4 + 2) << 4))) = (unsigned short)p23;
            *(unsigned short*)(hb + (rb + 3) * 256 + (col2 ^ ((l4 * 4 + 3) << 4))) = (unsigned short)(p23 >> 16);
        }

    // ================= stage 2: h2 = leaky(h1 @ w2.T + b2) ====================
#pragma unroll
    for (int nf = 0; nf < 8; ++nf) {
        float b = b2[nf * 16 + l15];
        acc[0][nf] = (f32x4){b, b, b, b};
        acc[1][nf] = acc[0][nf];
    }
#pragma unroll
    for (int kf = 0; kf < 4; ++kf) {
        S8 a[2];
#pragma unroll
        for (int mf = 0; mf < 2; ++mf)
            a[mf].s = *reinterpret_cast<const short8*>(hb + (mf * 16 + l15) * 256 + ((kf * 64 + l4 * 16) ^ (l15 << 4)));
#pragma unroll
        for (int nf = 0; nf < 8; ++nf) {
            S8 b; b.s = *reinterpret_cast<const short8*>(w2b + (nf * 16 + l15) * 128 + kf * 32 + l4 * 8);
#pragma unroll
            for (int mf = 0; mf < 2; ++mf)
                acc[mf][nf] = __builtin_amdgcn_mfma_f32_16x16x32_bf16(a[mf].s, b.s, acc[mf][nf], 0, 0, 0);
        }
    }
#pragma unroll
    for (int mf = 0; mf < 2; ++mf)
#pragma unroll
        for (int nf = 0; nf < 8; ++nf) {
            f32x4 v = acc[mf][nf];
#pragma unroll
            for (int q = 0; q < 4; ++q) v[q] = fmaxf(v[q], SLOPE * v[q]);
            unsigned p01 = cvt_pk_bf16(v[0], v[1]);
            unsigned p23 = cvt_pk_bf16(v[2], v[3]);
            int col2 = (nf * 16 + l15) * 2;
            int rb = mf * 16 + l4 * 4;
            *(unsigned short*)(hb + (rb + 0) * 256 + (col2 ^ ((l4 * 4 + 0) << 4))) = (unsigned short)p01;
            *(unsigned short*)(hb + (rb + 1) * 256 + (col2 ^ ((l4 * 4 + 1) << 4))) = (unsigned short)(p01 >> 16);
            *(unsigned short*)(hb + (rb + 2) * 256 + (col2 ^ ((l4 * 4 + 2) << 4))) = (unsigned short)p23;
            *(unsigned short*)(hb + (rb + 3) * 256 + (col2 ^ ((l4 * 4 + 3) << 4))) = (unsigned short)(p23 >> 16);
        }

    // ====== stage 3: W = (h2 @ w3.T + b3) * C ; e = vp[j] * W =================
    // prefetch the vp gather into registers; latency hides under stage-3 MFMAs
    int jb[2][4];
#pragma unroll
    for (int mf = 0; mf < 2; ++mf)
#pragma unroll
        for (int q = 0; q < 4; ++q)
            jb[mf][q] = ldsJ[wv][mf * 16 + l4 * 4 + q];
    unsigned vpr[2][4][8];
#pragma unroll
    for (int mf = 0; mf < 2; ++mf)
#pragma unroll
        for (int q = 0; q < 4; ++q)
#pragma unroll
            for (int nf = 0; nf < 8; ++nf)
                vpr[mf][q][nf] = vp[jb[mf][q] + nf * 16 + l15];

#pragma unroll
    for (int nf = 0; nf < 8; ++nf) {
        float b = b3[nf * 16 + l15];
        acc[0][nf] = (f32x4){b, b, b, b};
        acc[1][nf] = acc[0][nf];
    }
#pragma unroll
    for (int kf = 0; kf < 4; ++kf) {
        S8 a[2];
#pragma unroll
        for (int mf = 0; mf < 2; ++mf)
            a[mf].s = *reinterpret_cast<const short8*>(hb + (mf * 16 + l15) * 256 + ((kf * 64 + l4 * 16) ^ (l15 << 4)));
#pragma unroll
        for (int nf = 0; nf < 8; ++nf) {
            S8 b; b.s = *reinterpret_cast<const short8*>(w3b + (nf * 16 + l15) * 128 + kf * 32 + l4 * 8);
#pragma unroll
            for (int mf = 0; mf < 2; ++mf)
                acc[mf][nf] = __builtin_amdgcn_mfma_f32_16x16x32_bf16(a[mf].s, b.s, acc[mf][nf], 0, 0, 0);
        }
    }
    float Cq[2][4];
#pragma unroll
    for (int mf = 0; mf < 2; ++mf)
#pragma unroll
        for (int q = 0; q < 4; ++q)
            Cq[mf][q] = ldsC[wv][mf * 16 + l4 * 4 + q];
#pragma unroll
    for (int mf = 0; mf < 2; ++mf)
#pragma unroll
        for (int nf = 0; nf < 8; ++nf) {
            f32x4 v = acc[mf][nf];
            float ev[4];
#pragma unroll
            for (int q = 0; q < 4; ++q)
                ev[q] = __uint_as_float(vpr[mf][q][nf] << 16) * (v[q] * Cq[mf][q]);
            unsigned p01 = cvt_pk_bf16(ev[0], ev[1]);
            unsigned p23 = cvt_pk_bf16(ev[2], ev[3]);
            int col2 = (nf * 16 + l15) * 2;
            int rb = mf * 16 + l4 * 4;
            *(unsigned short*)(hb + (rb + 0) * 256 + (col2 ^ ((l4 * 4 + 0) << 4))) = (unsigned short)p01;
            *(unsigned short*)(hb + (rb + 1) * 256 + (col2 ^ ((l4 * 4 + 1) << 4))) = (unsigned short)(p01 >> 16);
            *(unsigned short*)(hb + (rb + 2) * 256 + (col2 ^ ((l4 * 4 + 2) << 4))) = (unsigned short)p23;
            *(unsigned short*)(hb + (rb + 3) * 256 + (col2 ^ ((l4 * 4 + 3) << 4))) = (unsigned short)(p23 >> 16);
        }

    // ====== stage 4: out = e @ (wo + I).T + bo (residual folded) ==============
#pragma unroll
    for (int nf = 0; nf < 8; ++nf) {
        float b = bo[nf * 16 + l15];
        acc[0][nf] = (f32x4){b, b, b, b};
        acc[1][nf] = acc[0][nf];
    }
#pragma unroll
    for (int kf = 0; kf < 4; ++kf) {
        S8 a[2];
#pragma unroll
        for (int mf = 0; mf < 2; ++mf)
            a[mf].s = *reinterpret_cast<const short8*>(hb + (mf * 16 + l15) * 256 + ((kf * 64 + l4 * 16) ^ (l15 << 4)));
#pragma unroll
        for (int nf = 0; nf < 8; ++nf) {
            S8 b; b.s = *reinterpret_cast<const short8*>(wob + (nf * 16 + l15) * 128 + kf * 32 + l4 * 8);
#pragma unroll
            for (int mf = 0; mf < 2; ++mf)
                acc[mf][nf] = __builtin_amdgcn_mfma_f32_16x16x32_bf16(a[mf].s, b.s, acc[mf][nf], 0, 0, 0);
        }
    }
    float* op = out + (size_t)e0 * 128;
#pragma unroll
    for (int mf = 0; mf < 2; ++mf)
#pragma unroll
        for (int nf = 0; nf < 8; ++nf)
#pragma unroll
            for (int q = 0; q < 4; ++q)
                op[(size_t)(mf * 16 + l4 * 4 + q) * 128 + nf * 16 + l15] = acc[mf][nf][q];
}

extern "C" void kernel_launch(void* const* d_in, const int* in_sizes, int n_in,
                              void* d_out, int out_size, void* d_ws, size_t ws_size,
                              hipStream_t stream) {
    const float* v        = (const float*)d_in[0];
    const float* dist     = (const float*)d_in[1];
    const float* dist_emb = (const float*)d_in[2];
    const int*   edge_idx = (const int*)d_in[3];
    const float* lin_w    = (const float*)d_in[4];
    const float* w1 = (const float*)d_in[5];
    const float* b1 = (const float*)d_in[6];
    const float* w2 = (const float*)d_in[7];
    const float* b2 = (const float*)d_in[8];
    const float* w3 = (const float*)d_in[9];
    const float* b3 = (const float*)d_in[10];
    const float* wo = (const float*)d_in[11];
    const float* bo = (const float*)d_in[12];
    float* out = (float*)d_out;

    const int nnodes = in_sizes[0] / 128;   // 50000
    const int E = in_sizes[1];              // 1600000 (multiple of 128)

    unsigned short* vp  = (unsigned short*)d_ws;            // [nnodes][128] bf16
    unsigned short* w1p = vp + (size_t)nnodes * 128;        // [128][64]
    unsigned short* w2b = w1p + 128 * 64;                   // [128][128]
    unsigned short* w3b = w2b + 128 * 128;
    unsigned short* wob = w3b + 128 * 128;

    prep_weights<<<64, 256, 0, stream>>>(w1, w2, w3, wo, w1p, w2b, w3b, wob);
    vp_gemm<<<(nnodes + 63) / 64, 256, 0, stream>>>(v, lin_w, vp, nnodes);
    fused_edge<<<E / 128, 256, 0, stream>>>(dist, dist_emb, edge_idx,
                                            b1, b2, b3, bo, vp,
                                            w1p, w2b, w3b, wob, out);
}